// Round 9
// baseline (292.204 us; speedup 1.0000x reference)
//
#include <hip/hip_runtime.h>

typedef unsigned short u16;
typedef __bf16 bf16x8 __attribute__((ext_vector_type(8)));
typedef float f32x4 __attribute__((ext_vector_type(4)));

#define Bn 4
#define Sn 2048
#define Dn 1024
#define Hn 16
#define HDn 64

__device__ inline u16 f2bf(float f) {
  unsigned u = __builtin_bit_cast(unsigned, f);
  u += 0x7fffu + ((u >> 16) & 1u);
  return (u16)(u >> 16);
}

// async global->LDS DMA, 16B/lane; LDS dest = wave base + lane*16 [m97]
__device__ __forceinline__ void gl2lds16(const u16* g, u16* l) {
  __builtin_amdgcn_global_load_lds(
      (const __attribute__((address_space(1))) unsigned int*)g,
      (__attribute__((address_space(3))) unsigned int*)l, 16, 0, 0);
}

__device__ __forceinline__ float fexp2(float x) {
  return __builtin_amdgcn_exp2f(x);
}

// pack two f32 -> two bf16 (truncating) in one v_perm
__device__ __forceinline__ unsigned pk_bf_trunc(float lo, float hi) {
  return __builtin_amdgcn_perm(__builtin_bit_cast(unsigned, hi),
                               __builtin_bit_cast(unsigned, lo), 0x07060302u);
}

// ---- elementwise fp32 -> bf16 convert (x) ----
__global__ __launch_bounds__(256) void cvt4(const float* __restrict__ in,
                                            u16* __restrict__ out, int n4) {
  int i = blockIdx.x * 256 + threadIdx.x;
  if (i < n4) {
    float4 v = ((const float4*)in)[i];
    ushort4 o;
    o.x = f2bf(v.x); o.y = f2bf(v.y); o.z = f2bf(v.z); o.w = f2bf(v.w);
    ((ushort4*)out)[i] = o;
  }
}

// ---- transpose + convert 4 weights in one launch: out[z][n][k] = in_z[k][n] ----
__global__ __launch_bounds__(256) void tcvt4(const float* __restrict__ w0,
                                             const float* __restrict__ w1,
                                             const float* __restrict__ w2,
                                             const float* __restrict__ w3,
                                             u16* __restrict__ out) {
  __shared__ u16 tile[32][33];
  const float* in = (blockIdx.z == 0) ? w0 : (blockIdx.z == 1) ? w1
                   : (blockIdx.z == 2) ? w2 : w3;
  u16* dst = out + (size_t)blockIdx.z * Dn * Dn;
  int bx = blockIdx.x * 32;
  int by = blockIdx.y * 32;
  int tx = threadIdx.x & 31;
  int ty = threadIdx.x >> 5;
#pragma unroll
  for (int r = 0; r < 32; r += 8)
    tile[ty + r][tx] = f2bf(in[(size_t)(by + ty + r) * Dn + bx + tx]);
  __syncthreads();
#pragma unroll
  for (int r = 0; r < 32; r += 8)
    dst[(size_t)(bx + ty + r) * Dn + by + tx] = tile[tx][ty + r];
}

#define MFMA16(a, b, c) __builtin_amdgcn_mfma_f32_16x16x32_bf16(a, b, c, 0, 0, 0)
#define VM6 asm volatile("s_waitcnt vmcnt(6)" ::: "memory")
#define VM0 asm volatile("s_waitcnt vmcnt(0)" ::: "memory")

// ==== fused QKV gemm v2: 256x256 tile, BK=64, 8 waves (2Mx4N), dbuf ====
// M=8192, N=3072 (Q|K|V), K=1024. Per-wave output 128x64 (acc[8][4]).
// Rationale (R8 arithmetic): per-K-tile overhead (~2000 cyc: barrier
// convergence + vmcnt + stage issue) is structure-invariant (m201's 256^2
// also ~2900 cyc/tile); 256^2 does 4x the MFLOP of 128x256 at the same
// per-tile cost. Grid 32x12 = 384 blocks, 1 block/CU (128KB LDS), runs as
// a 256+128 two-round schedule (~75% balance) -- amortization still nets
// ~1.5x vs R8's 62us.
// LDS: 2 bufs x 4 regions x 16KB = 128KB. Regions (128 rows x 64 cols):
//   rg0: A rows 0..127 | rg1: A rows 128..255 (wave row wr reads rg[wr])
//   rg2: B rows 0..127 | rg3: B rows 128..255 (wave col wc reads rg[2+(wc>>1)])
// Per K-tile (ONE barrier): stage tile T+1 -> buf d^1 (8 gl2lds); per
// k-step {read 8 A + 4 B frags, 32 MFMA}; vmcnt(0) (T+1's loads issued a
// full tile ago -> drain cheap); s_barrier. WAR on buf d^1 safe: its last
// ds_reads (tile T-1) retired before T-1's closing barrier, which precedes
// this tile's stage issue (same pattern as m201's 2-buffer template).
// Swizzle: identical involution as R4-R8 (verified SQ_LDS_BANK_CONFLICT=0).
__global__ __launch_bounds__(512, 2) void gemm_qkv(const u16* __restrict__ A,
                                                   const u16* __restrict__ Bt,
                                                   u16* __restrict__ qkb,
                                                   u16* __restrict__ vt,
                                                   float qscale) {
  __shared__ __attribute__((aligned(16))) u16 S[2][4][8192];  // 128 KB

  const int tid = threadIdx.x;
  const int lane = tid & 63;
  const int lcol = lane & 15;
  const int quad = lane >> 4;
  const int wave = tid >> 6;
  const int wr = wave >> 2;  // 0..1 (M)
  const int wc = wave & 3;   // 0..3 (N)

  // XCD swizzle: xcd = bid&7 owns 4 M-tiles x 12 N-tiles; mt-minor order
  // -> A chunk (2MB) L2-resident, consecutive bids share the B panel.
  const int bid = blockIdx.x;
  const int idx = bid >> 3;                             // 0..47
  const int bm = (((bid & 7) << 2) + (idx & 3)) * 256;  // M tile 0..31
  const int bn = (idx >> 2) * 256;                      // N tile 0..11

  // staging source pointers: 4 regions x 2 chunks (8KB each) per thread
  const u16* srcp[4][2];
#pragma unroll
  for (int rg = 0; rg < 4; rg++) {
#pragma unroll
    for (int j = 0; j < 2; j++) {
      int o = j * 8192 + tid * 16;            // physical byte offset in region
      int l = o ^ (((o >> 8) & 7) << 4);      // logical byte offset (involution)
      int rho = l >> 7;                       // local row 0..127
      int c2 = (l >> 1) & 63;                 // u16 col 0..63
      int gr;
      if (rg == 0)      gr = bm + rho;
      else if (rg == 1) gr = bm + 128 + rho;
      else if (rg == 2) gr = bn + rho;
      else              gr = bn + 128 + rho;
      const u16* base = (rg < 2) ? A : Bt;
      srcp[rg][j] = base + (size_t)gr * Dn + c2;
    }
  }

  auto stg = [&](int rg, int buf, int tile) {
    if (tile >= 16) return;  // tail guard (T=15 stages tile 16 -> skipped)
    const int k0 = tile << 6;
    u16* d = &S[buf][rg][tid * 8];
    gl2lds16(srcp[rg][0] + k0, d);
    gl2lds16(srcp[rg][1] + k0, d + 4096);
  };

  f32x4 acc[8][4];
#pragma unroll
  for (int i = 0; i < 8; i++)
#pragma unroll
    for (int j = 0; j < 4; j++) acc[i][j] = (f32x4){0.f, 0.f, 0.f, 0.f};

  // ds_read swizzled column-byte offsets (row bits 1-3 == lcol bits 1-3;
  // region-row = {mi*16+lcol} or {(wc&1)*64 + ni*16+lcol} -- bit6 doesn't
  // touch bits 1-3, so SW from lcol is correct for all frags)
  const int SW = (lcol & 14) << 3;
  const int cs0 = (quad * 16) ^ SW;         // k-step 0 (cols 0-31)
  const int cs1 = (64 + quad * 16) ^ SW;    // k-step 1 (cols 32-63)

// A frag mi (0..7): region wr, row mi*16+lcol
#define AR2(D, MI, K)                                                        \
  (*(const bf16x8*)((const char*)&S[D][wr][0] +                              \
      (((MI) * 16 + lcol) * 128 + ((K) ? cs1 : cs0))))
// B frag ni (0..3): region 2+(wc>>1), row (wc&1)*64 + ni*16+lcol
#define BR2(D, NI, K)                                                        \
  (*(const bf16x8*)((const char*)&S[D][2 + (wc >> 1)][0] +                   \
      ((((wc & 1) * 64 + (NI) * 16 + lcol)) * 128 + ((K) ? cs1 : cs0))))

#define KSTEP2(D, K)                                                         \
  {                                                                          \
    bf16x8 af[8], bf[4];                                                     \
    _Pragma("unroll") for (int mi = 0; mi < 8; mi++) af[mi] = AR2(D, mi, K); \
    _Pragma("unroll") for (int ni = 0; ni < 4; ni++) bf[ni] = BR2(D, ni, K); \
    __builtin_amdgcn_s_setprio(1);                                           \
    _Pragma("unroll") for (int ni = 0; ni < 4; ni++)                         \
      _Pragma("unroll") for (int mi = 0; mi < 8; mi++)                       \
        acc[mi][ni] = MFMA16(af[mi], bf[ni], acc[mi][ni]);                   \
    __builtin_amdgcn_s_setprio(0);                                           \
  }

#define KT2(D, T)                                                            \
  {                                                                          \
    stg(0, (D) ^ 1, (T) + 1); stg(1, (D) ^ 1, (T) + 1);                      \
    stg(2, (D) ^ 1, (T) + 1); stg(3, (D) ^ 1, (T) + 1);                      \
    __builtin_amdgcn_sched_barrier(0);                                       \
    KSTEP2(D, 0)                                                             \
    KSTEP2(D, 1)                                                             \
    VM0;                                                                     \
    __builtin_amdgcn_s_barrier();                                            \
    __builtin_amdgcn_sched_barrier(0);                                       \
  }

  // prologue: stage tile0 -> buf0
  stg(0, 0, 0); stg(1, 0, 0); stg(2, 0, 0); stg(3, 0, 0);
  VM0;
  __builtin_amdgcn_s_barrier();
  __builtin_amdgcn_sched_barrier(0);

#pragma unroll 1
  for (int I = 0; I < 8; ++I) {
    KT2(0, 2 * I)
    KT2(1, 2 * I + 1)
  }
#undef KT2
#undef KSTEP2
#undef AR2
#undef BR2

  // ---- fused epilogue (per-wave 128x64 at bm+wr*128, bn+wc*64) ----
  const int rb = bm + wr * 128 + quad * 4;
  const int cb = bn + wc * 64 + lcol;
  if (bn >= 2048) {
#pragma unroll
    for (int ai = 0; ai < 8; ai++) {
#pragma unroll
      for (int bj = 0; bj < 4; bj++) {
        int row0 = rb + ai * 16;
        int s = row0 & (Sn - 1);
        int bb = row0 >> 11;
        int vcol = cb + bj * 16 - 2048;
        int bh = (bb << 4) + (vcol >> 6);
        int hd = vcol & 63;
        unsigned d0 = (unsigned)f2bf(acc[ai][bj][0]) |
                      ((unsigned)f2bf(acc[ai][bj][1]) << 16);
        unsigned d1 = (unsigned)f2bf(acc[ai][bj][2]) |
                      ((unsigned)f2bf(acc[ai][bj][3]) << 16);
        *(uint2*)(vt + ((size_t)bh * HDn + hd) * Sn + s) = (uint2){d0, d1};
      }
    }
  } else {
    const float scale = (bn < 1024) ? qscale : 1.0f;
#pragma unroll
    for (int ai = 0; ai < 8; ai++) {
#pragma unroll
      for (int bj = 0; bj < 4; bj++) {
        int row0 = rb + ai * 16;
        int col = cb + bj * 16;
#pragma unroll
        for (int r = 0; r < 4; r++)
          qkb[(size_t)(row0 + r) * 2048 + col] = f2bf(acc[ai][bj][r] * scale);
      }
    }
  }
}

// ==== output gemm (frozen): 128x256 / BK=64 / triple-buffer ====
#define SRCP_INIT(APTR, BPTR)                                                \
  const u16* srcp[3][2];                                                     \
  _Pragma("unroll") for (int rg = 0; rg < 3; rg++) {                         \
    _Pragma("unroll") for (int j = 0; j < 2; j++) {                          \
      int o = j * 8192 + tid * 16;                                           \
      int l = o ^ (((o >> 8) & 7) << 4);                                     \
      int rho = l >> 7;                                                      \
      int c2 = (l >> 1) & 63;                                                \
      int gr;                                                                \
      if (rg == 0)      gr = bm + rho;                                       \
      else if (rg == 1) gr = bn + ((rho >> 5) << 6) + (rho & 31);            \
      else              gr = bn + ((rho >> 5) << 6) + 32 + (rho & 31);       \
      const u16* base = (rg == 0) ? (APTR) : (BPTR);                         \
      srcp[rg][j] = base + (size_t)gr * Dn + c2;                             \
    }                                                                        \
  }

#define ARD(D, Q, F, K)                                                      \
  (*(const bf16x8*)((const char*)&S[D][0][0] +                               \
      ((wr * 64 + (Q) * 32 + (F) * 16 + lcol) * 128 + ((K) ? cs1 : cs0))))
#define BRD(D, NI, K)                                                        \
  (*(const bf16x8*)((const char*)&S[D][1 + ((NI) >> 1)][0] +                 \
      ((wc * 32 + ((NI) & 1) * 16 + lcol) * 128 + ((K) ? cs1 : cs0))))

#define KTILE(D, DN, T, WAIT)                                                \
  {                                                                          \
    stg(0, DN, (T) + 2); stg(1, DN, (T) + 2); stg(2, DN, (T) + 2);           \
    __builtin_amdgcn_sched_barrier(0);                                       \
    bf16x8 a00 = ARD(D, 0, 0, 0), a10 = ARD(D, 0, 1, 0);                     \
    bf16x8 a20 = ARD(D, 1, 0, 0), a30 = ARD(D, 1, 1, 0);                     \
    bf16x8 bk0[4], bk1[4];                                                   \
    _Pragma("unroll") for (int ni = 0; ni < 4; ni++) bk0[ni] = BRD(D, ni, 0);\
    bf16x8 a01 = ARD(D, 0, 0, 1), a11 = ARD(D, 0, 1, 1);                     \
    bf16x8 a21 = ARD(D, 1, 0, 1), a31 = ARD(D, 1, 1, 1);                     \
    _Pragma("unroll") for (int ni = 0; ni < 4; ni++) bk1[ni] = BRD(D, ni, 1);\
    __builtin_amdgcn_s_setprio(1);                                           \
    _Pragma("unroll") for (int ni = 0; ni < 4; ni++) {                       \
      acc[0][ni] = MFMA16(a00, bk0[ni], acc[0][ni]);                         \
      acc[1][ni] = MFMA16(a10, bk0[ni], acc[1][ni]);                         \
      acc[2][ni] = MFMA16(a20, bk0[ni], acc[2][ni]);                         \
      acc[3][ni] = MFMA16(a30, bk0[ni], acc[3][ni]);                         \
    }                                                                        \
    _Pragma("unroll") for (int ni = 0; ni < 4; ni++) {                       \
      acc[0][ni] = MFMA16(a01, bk1[ni], acc[0][ni]);                         \
      acc[1][ni] = MFMA16(a11, bk1[ni], acc[1][ni]);                         \
      acc[2][ni] = MFMA16(a21, bk1[ni], acc[2][ni]);                         \
      acc[3][ni] = MFMA16(a31, bk1[ni], acc[3][ni]);                         \
    }                                                                        \
    __builtin_amdgcn_s_setprio(0);                                           \
    WAIT;                                                                    \
    __builtin_amdgcn_s_barrier();                                            \
    __builtin_amdgcn_sched_barrier(0);                                       \
  }

#define KLOOP                                                                \
  stg(0, 0, 0); stg(1, 0, 0); stg(2, 0, 0);                                  \
  stg(0, 1, 1); stg(1, 1, 1); stg(2, 1, 1);                                  \
  VM6;                                                                       \
  __builtin_amdgcn_s_barrier();                                              \
  __builtin_amdgcn_sched_barrier(0);                                         \
  _Pragma("unroll 1") for (int I = 0; I < 5; ++I) {                          \
    const int T0 = 3 * I;                                                    \
    KTILE(0, 2, T0, VM6)                                                     \
    KTILE(1, 0, T0 + 1, VM6)                                                 \
    KTILE(2, 1, T0 + 2, if (I == 4) { VM0; } else { VM6; })                  \
  }                                                                          \
  KTILE(0, 2, 15, )

__global__ __launch_bounds__(512, 2) void gemm_out(const u16* __restrict__ A,
                                                   const u16* __restrict__ Bt,
                                                   float* __restrict__ Cout,
                                                   const float* __restrict__ bias) {
  __shared__ __attribute__((aligned(16))) u16 S[3][3][8192];  // 144 KB

  const int tid = threadIdx.x;
  const int lane = tid & 63;
  const int lcol = lane & 15;
  const int quad = lane >> 4;
  const int wave = tid >> 6;
  const int wr = wave >> 2;  // 0..1 (M)
  const int wc = wave & 3;   // 0..3 (N)

  // 256 blocks: xcd = bid&7 owns 8 M-tiles x 4 N-tiles (A 2MB + B 2MB L2-fit)
  const int bid = blockIdx.x;
  const int idx = bid >> 3;                             // 0..31
  const int bm = (((bid & 7) << 3) + (idx & 7)) * 128;  // M tile 0..63
  const int bn = (idx >> 3) * 256;                      // N tile 0..3

  SRCP_INIT(A, Bt)

  auto stg = [&](int rg, int buf, int tile) {
    if (tile >= 16) return;
    const int k0 = tile << 6;
    u16* d = &S[buf][rg][tid * 8];
    gl2lds16(srcp[rg][0] + k0, d);
    gl2lds16(srcp[rg][1] + k0, d + 4096);
  };

  f32x4 acc[4][4];
#pragma unroll
  for (int i = 0; i < 4; i++)
#pragma unroll
    for (int j = 0; j < 4; j++) acc[i][j] = (f32x4){0.f, 0.f, 0.f, 0.f};

  const int SW = (lcol & 14) << 3;
  const int cs0 = (quad * 16) ^ SW;
  const int cs1 = (64 + quad * 16) ^ SW;

  KLOOP

  // ---- epilogue: fp32 + bias ----
  const int rb = bm + wr * 64 + quad * 4;
  const int cb = bn + wc * 64 + lcol;
  float bv[4];
#pragma unroll
  for (int ni = 0; ni < 4; ni++) bv[ni] = bias[cb + ni * 16];
#pragma unroll
  for (int mi = 0; mi < 4; mi++) {
#pragma unroll
    for (int ni = 0; ni < 4; ni++) {
      int row0 = rb + mi * 16;
      int col = cb + ni * 16;
#pragma unroll
      for (int r = 0; r < 4; r++)
        Cout[(size_t)(row0 + r) * Dn + col] = acc[mi][ni][r] + bv[ni];
    }
  }
}

// ---- causal flash attention v8 (frozen from R8) ----
__global__ __launch_bounds__(256, 2) void attn5(const u16* __restrict__ QK,
                                                const u16* __restrict__ Vt,
                                                u16* __restrict__ ctx) {
  __shared__ __attribute__((aligned(16))) u16 Ks2[2][2][64][32];   // 16 KB
  __shared__ __attribute__((aligned(16))) u16 Vts2[2][2][64][32];  // 16 KB
  __shared__ __attribute__((aligned(16))) u16 Pt[2][4][32][72];    // 36 KB

  const int bh = blockIdx.x;
  const int b = bh >> 4, h = bh & 15;
  const int pair = blockIdx.y;           // 0..7
  const int t = threadIdx.x;
  const int w = t >> 6;
  const int lane = t & 63;
  const int lcol = lane & 15;
  const int quad = lane >> 4;
  const int qw0 = pair * 128 + w * 32;          // short strip wave base
  const int qw1 = (15 - pair) * 128 + w * 32;   // long strip wave base

  const size_t qkbase = ((size_t)b * Sn) * 2048 + h * HDn;
  const size_t obase = ((size_t)b * Sn) * Dn + h * HDn;
  const size_t vbase = ((size_t)bh * HDn) * Sn;

  bf16x8 qf[2][2][2];  // [strip][qb][kc]
#pragma unroll
  for (int si = 0; si < 2; si++) {
    const int qws = si ? qw1 : qw0;
#pragma unroll
    for (int qb = 0; qb < 2; qb++) {
      const u16* qp = QK + qkbase + (size_t)(qws + qb * 16 + lcol) * 2048 + quad * 8;
      qf[si][qb][0] = *(const bf16x8*)qp;
      qf[si][qb][1] = *(const bf16x8*)(qp + 32);
    }
  }

  bf16x8 onesf;
#pragma unroll
  for (int i = 0; i < 8; i++) onesf[i] = (__bf16)1.0f;

  f32x4 o[2][2][4];   // [strip][qb][nb]
  f32x4 ls[2][2];     // [strip][qb] MFMA row-sum accumulators
#pragma unroll
  for (int si = 0; si < 2; si++) {
#pragma unroll
    for (int qb = 0; qb < 2; qb++) {
      ls[si][qb] = (f32x4){0.f, 0.f, 0.f, 0.f};
#pragma unroll
      for (int nb = 0; nb < 4; nb++) o[si][qb][nb] = (f32x4){0.f, 0.f, 0.f, 0.f};
    }
  }

  const int srow = lane >> 2;
  const int sseg = ((lane & 3) ^ ((lane >> 3) & 3)) * 8;
  const u16* kp0 = QK + qkbase + 1024 + (size_t)(w * 16 + srow) * 2048 + sseg;
  const u16* vp0 = Vt + vbase + (size_t)(w * 16 + srow) * Sn + sseg;
  u16* ksl = &Ks2[0][0][0][0] + w * 512 + lane * 8;
  u16* vsl = &Vts2[0][0][0][0] + w * 512 + lane * 8;

  const int rsw = (quad ^ ((lcol >> 1) & 3)) * 8;

  auto stg_kv = [&](int bs, int j0) {
    const u16* kp = kp0 + (size_t)j0 * 2048;
    const u16* vp = vp0 + j0;
    u16* kd = ksl + bs * 4096;
    u16* vd = vsl + bs * 4096;
    gl2lds16(kp, kd);
    gl2lds16(kp + 32, kd + 2048);
    gl2lds16(vp, vd);
    gl2lds16(vp + 32, vd + 2048);
  };

  auto qk_strip = [&](int si, f32x4 (*s)[2], int bs) {
    __builtin_amdgcn_s_setprio(1);
#pragma unroll
    for (int mb = 0; mb < 4; mb++) {
      bf16x8 kf0 = *(const bf16x8*)(&Ks2[bs][0][mb * 16 + lcol][rsw]);
      bf16x8 kf1 = *(const bf16x8*)(&Ks2[bs][1][mb * 16 + lcol][rsw]);
#pragma unroll
      for (int qb = 0; qb < 2; qb++) {
        f32x4 a = (f32x4){0.f, 0.f, 0.f, 0.f};
        a = MFMA16(kf0, qf[si][qb][0], a);
        a = MFMA16(kf1, qf[si][qb][1], a);
        s[mb][qb] = a;
      }
    }
    __builtin_amdgcn_s_setprio(0);
  };

  auto sm_strip = [&](int si, int qw, int j0, f32x4 (*s)[2]) {
    const bool needmask = (j0 + 63 > qw);
#pragma unroll
    for (int qb = 0; qb < 2; qb++) {
      const int qrow = qw + qb * 16 + lcol;
#pragma unroll
      for (int mb = 0; mb < 4; mb++) {
        float p[4];
#pragma unroll
        for (int r = 0; r < 4; r++) p[r] = fexp2(s[mb][qb][r]);
        if (needmask) {
          const int kvb = j0 + mb * 16 + quad * 4;
#pragma unroll
          for (int r = 0; r < 4; r++)
            if (kvb + r > qrow) p[r] = 0.f;
        }
        unsigned d0 = pk_bf_trunc(p[0], p[1]);
        unsigned d1 = pk_bf_trunc(p[2], p[3]);
        *(uint2*)(&Pt[si][w][qb * 16 + lcol][mb * 16 + quad * 4]) = (uint2){d0, d1};
      }
    }
  };

  auto pv_strip = [&](int si, int bs) {
    __builtin_amdgcn_s_setprio(1);
#pragma unroll
    for (int c = 0; c < 2; c++) {
      bf16x8 pf0 = *(const bf16x8*)(&Pt[si][w][lcol][c * 32 + quad * 8]);
      bf16x8 pf1 = *(const bf16x8*)(&Pt[si][w][16 + lcol][c * 32 + quad * 8]);
      ls[si][0] = MFMA16(onesf, pf0, ls[si][0]);
      ls[si][1] = MFMA16(onesf, pf1, ls[si][1]);
#pragma unroll
      for (int nb = 0; nb < 4; nb++) {
        bf16x8 vf = *(const bf16x8*)(&Vts2[bs][c][nb * 16 + lcol][rsw]);
        o[si][0][nb] = MFMA16(vf, pf0, o[si][0][nb]);
        o[si][1][nb] = MFMA16(vf, pf1, o[si][1][nb]);
      }
    }
    __builtin_amdgcn_s_setprio(0);
  };

  const int n_kv = (15 - pair) * 128 + 128;  // long strip upper bound
  const int nit = n_kv >> 6;

  stg_kv(0, 0);
#pragma unroll 1
  for (int it = 0; it < nit; ++it) {
    const int j0 = it << 6;
    const int bs = it & 1;
    if (it + 1 < nit) {
      stg_kv(bs ^ 1, j0 + 64);
      asm volatile("s_waitcnt vmcnt(4)" ::: "memory");
    } else {
      asm volatile("s_waitcnt vmcnt(0)" ::: "memory");
    }
    __builtin_amdgcn_s_barrier();
    __builtin_amdgcn_sched_barrier(0);

    const bool a0 = (j0 <= qw0 + 31);
    f32x4 s1[4][2], s0[4][2];
    qk_strip(1, s1, bs);
    if (a0) qk_strip(0, s0, bs);
    sm_strip(1, qw1, j0, s1);
    if (a0) sm_strip(0, qw0, j0, s0);
    pv_strip(1, bs);
    if (a0) pv_strip(0, bs);

    __builtin_amdgcn_s_barrier();
    __builtin_amdgcn_sched_barrier(0);
  }

#pragma unroll
  for (int si = 0; si < 2; si++) {
    const int qws = si ? qw1 : qw0;
#pragma unroll
    for (int qb = 0; qb < 2; qb++) {
      float inv = 1.0f / ls[si][qb][0];
#pragma unroll
      for (int nb = 0; nb < 4; nb++) {
        unsigned d0 = (unsigned)f2bf(o[si][qb][nb][0] * inv) |
                      ((unsigned)f2bf(o[si][qb][nb][1] * inv) << 16);
        unsigned d1 = (unsigned)f2bf(o[si][qb][nb][2] * inv) |
                      ((unsigned)f2bf(o[si][qb][nb][3] * inv) << 16);
        u16* p = ctx + obase + (size_t)(qws + qb * 16 + lcol) * Dn + nb * 16 + quad * 4;
        *(uint2*)p = (uint2){d0, d1};
      }
    }
  }
}

extern "C" void kernel_launch(void* const* d_in, const int* in_sizes, int n_in,
                              void* d_out, int out_size, void* d_ws, size_t ws_size,
                              hipStream_t stream) {
  const float* x  = (const float*)d_in[0];
  const float* Wq = (const float*)d_in[1];
  const float* Wk = (const float*)d_in[2];
  const float* Wv = (const float*)d_in[3];
  const float* Wo = (const float*)d_in[4];
  const float* bo = (const float*)d_in[5];
  float* out = (float*)d_out;

  const size_t BSD = (size_t)Bn * Sn * Dn;
  const size_t DD = (size_t)Dn * Dn;

  u16* xb    = (u16*)d_ws;           // BSD
  u16* wall  = xb + BSD;             // 4*DD  (Wq^T, Wk^T, Wv^T, Wo^T)
  u16* qkb   = wall + 4 * DD;        // 2*BSD
  u16* vt    = qkb + 2 * BSD;        // BSD
  u16* cb    = vt + BSD;             // BSD

  cvt4<<<(int)(BSD / 4 / 256), 256, 0, stream>>>(x, xb, (int)(BSD / 4));
  tcvt4<<<dim3(Dn / 32, Dn / 32, 4), 256, 0, stream>>>(Wq, Wk, Wv, Wo, wall);

  // fused QKV projection: 256x256 tiles, 384 blocks, double-buffer
  gemm_qkv<<<dim3(384), 512, 0, stream>>>(xb, wall, qkb, vt,
                                          0.125f * 1.44269504f);

  attn5<<<dim3(Bn * Hn, 8), 256, 0, stream>>>(qkb, vt, cb);

  // output projection: 128x256 tiles, 256 blocks (1 perfect round)
  gemm_out<<<dim3(256), 512, 0, stream>>>(cb, wall + 3 * DD, out, bo);
}

// Round 10
// 239.869 us; speedup vs baseline: 1.2182x; 1.2182x over previous
//
#include <hip/hip_runtime.h>

typedef unsigned short u16;
typedef __bf16 bf16x8 __attribute__((ext_vector_type(8)));
typedef float f32x4 __attribute__((ext_vector_type(4)));

#define Bn 4
#define Sn 2048
#define Dn 1024
#define Hn 16
#define HDn 64

__device__ inline u16 f2bf(float f) {
  unsigned u = __builtin_bit_cast(unsigned, f);
  u += 0x7fffu + ((u >> 16) & 1u);
  return (u16)(u >> 16);
}

// async global->LDS DMA, 16B/lane; LDS dest = wave base + lane*16 [m97]
__device__ __forceinline__ void gl2lds16(const u16* g, u16* l) {
  __builtin_amdgcn_global_load_lds(
      (const __attribute__((address_space(1))) unsigned int*)g,
      (__attribute__((address_space(3))) unsigned int*)l, 16, 0, 0);
}

__device__ __forceinline__ float fexp2(float x) {
  return __builtin_amdgcn_exp2f(x);
}

// pack two f32 -> two bf16 (truncating) in one v_perm
__device__ __forceinline__ unsigned pk_bf_trunc(float lo, float hi) {
  return __builtin_amdgcn_perm(__builtin_bit_cast(unsigned, hi),
                               __builtin_bit_cast(unsigned, lo), 0x07060302u);
}

// ---- elementwise fp32 -> bf16 convert (x) ----
__global__ __launch_bounds__(256) void cvt4(const float* __restrict__ in,
                                            u16* __restrict__ out, int n4) {
  int i = blockIdx.x * 256 + threadIdx.x;
  if (i < n4) {
    float4 v = ((const float4*)in)[i];
    ushort4 o;
    o.x = f2bf(v.x); o.y = f2bf(v.y); o.z = f2bf(v.z); o.w = f2bf(v.w);
    ((ushort4*)out)[i] = o;
  }
}

// ---- transpose + convert 4 weights in one launch: out[z][n][k] = in_z[k][n] ----
__global__ __launch_bounds__(256) void tcvt4(const float* __restrict__ w0,
                                             const float* __restrict__ w1,
                                             const float* __restrict__ w2,
                                             const float* __restrict__ w3,
                                             u16* __restrict__ out) {
  __shared__ u16 tile[32][33];
  const float* in = (blockIdx.z == 0) ? w0 : (blockIdx.z == 1) ? w1
                   : (blockIdx.z == 2) ? w2 : w3;
  u16* dst = out + (size_t)blockIdx.z * Dn * Dn;
  int bx = blockIdx.x * 32;
  int by = blockIdx.y * 32;
  int tx = threadIdx.x & 31;
  int ty = threadIdx.x >> 5;
#pragma unroll
  for (int r = 0; r < 32; r += 8)
    tile[ty + r][tx] = f2bf(in[(size_t)(by + ty + r) * Dn + bx + tx]);
  __syncthreads();
#pragma unroll
  for (int r = 0; r < 32; r += 8)
    dst[(size_t)(bx + ty + r) * Dn + by + tx] = tile[tx][ty + r];
}

#define MFMA16(a, b, c) __builtin_amdgcn_mfma_f32_16x16x32_bf16(a, b, c, 0, 0, 0)
#define VM6 asm volatile("s_waitcnt vmcnt(6)" ::: "memory")
#define VM0 asm volatile("s_waitcnt vmcnt(0)" ::: "memory")

// ==== fused QKV gemm v3: 256x256 tile, BK=64, 8 waves, SPILL-FREE retry ====
// R9 failed on register spill (WRITE_SIZE 49->74MB = scratch traffic).
// v3 changes vs R9 (dataflow identical):
//  (1) A-frags read 4 at a time (two 16-MFMA halves per k-step): live
//      operand regs 48 -> 32.
//  (2) srcp: 4 base pointers only; chunk-1 source = chunk-0 + 64*Dn
//      (+8192 phys bytes doesn't touch XOR bits 8-10 -> same involution,
//      row+64, col unchanged -- proven mapping).
// Live estimate: acc 128 + af 16 + bf 16 + srcp 8 + addr ~25 = ~190 < 256.
// Per-tile model (corrected MFMA rate 19.4 cyc/SIMD): MFMA 2480 + LDS 2304
// -> ~3300 cyc/tile; 16 tiles x 1.5 rounds ~= 35-40us vs R8's 62.
// LDS: 2 bufs x 4 regions x 16KB = 128KB. Regions (128 rows x 64 cols):
//   rg0: A rows 0..127 | rg1: A rows 128..255 | rg2: B 0..127 | rg3: B 128..255
// Per K-tile: stage T+1 -> buf d^1 (8 gl2lds); 2 k-steps x 2 halves of
// 16 MFMA; VM0 (stages had a full tile to land); s_barrier.
// Swizzle: involution phys = logical ^ (((o>>8)&7)<<4), verified 0-conflict.
__global__ __launch_bounds__(512, 2) void gemm_qkv(const u16* __restrict__ A,
                                                   const u16* __restrict__ Bt,
                                                   u16* __restrict__ qkb,
                                                   u16* __restrict__ vt,
                                                   float qscale) {
  __shared__ __attribute__((aligned(16))) u16 S[2][4][8192];  // 128 KB

  const int tid = threadIdx.x;
  const int lane = tid & 63;
  const int lcol = lane & 15;
  const int quad = lane >> 4;
  const int wave = tid >> 6;
  const int wr = wave >> 2;  // 0..1 (M)
  const int wc = wave & 3;   // 0..3 (N)

  // XCD swizzle: xcd = bid&7 owns 4 M-tiles x 12 N-tiles; mt-minor order.
  const int bid = blockIdx.x;
  const int idx = bid >> 3;                             // 0..47
  const int bm = (((bid & 7) << 2) + (idx & 3)) * 256;  // M tile 0..31
  const int bn = (idx >> 2) * 256;                      // N tile 0..11

  // staging source: 4 base pointers (chunk 1 = +64*Dn)
  const u16* srcp[4];
#pragma unroll
  for (int rg = 0; rg < 4; rg++) {
    int o = tid * 16;                       // physical byte offset, chunk 0
    int l = o ^ (((o >> 8) & 7) << 4);      // logical byte offset (involution)
    int rho = l >> 7;                       // local row 0..63 (chunk 0)
    int c2 = (l >> 1) & 63;                 // u16 col 0..63
    int gr;
    if (rg == 0)      gr = bm + rho;
    else if (rg == 1) gr = bm + 128 + rho;
    else if (rg == 2) gr = bn + rho;
    else              gr = bn + 128 + rho;
    const u16* base = (rg < 2) ? A : Bt;
    srcp[rg] = base + (size_t)gr * Dn + c2;
  }

  auto stg = [&](int rg, int buf, int tile) {
    if (tile >= 16) return;  // tail guard
    const int k0 = tile << 6;
    u16* d = &S[buf][rg][tid * 8];
    gl2lds16(srcp[rg] + k0, d);
    gl2lds16(srcp[rg] + (size_t)64 * Dn + k0, d + 4096);
  };

  f32x4 acc[8][4];
#pragma unroll
  for (int i = 0; i < 8; i++)
#pragma unroll
    for (int j = 0; j < 4; j++) acc[i][j] = (f32x4){0.f, 0.f, 0.f, 0.f};

  // ds_read swizzled column-byte offsets (row bits 1-3 == lcol bits 1-3)
  const int SW = (lcol & 14) << 3;
  const int cs0 = (quad * 16) ^ SW;         // k-step 0 (cols 0-31)
  const int cs1 = (64 + quad * 16) ^ SW;    // k-step 1 (cols 32-63)

// A frag mi (0..7): region wr, row mi*16+lcol
#define AR3(D, MI, K)                                                        \
  (*(const bf16x8*)((const char*)&S[D][wr][0] +                              \
      (((MI) * 16 + lcol) * 128 + ((K) ? cs1 : cs0))))
// B frag ni (0..3): region 2+(wc>>1), row (wc&1)*64 + ni*16+lcol
#define BR3(D, NI, K)                                                        \
  (*(const bf16x8*)((const char*)&S[D][2 + (wc >> 1)][0] +                   \
      ((((wc & 1) * 64 + (NI) * 16 + lcol)) * 128 + ((K) ? cs1 : cs0))))

// one k-step: bf[4] once, then two halves of {af[4] read, 16 MFMA}
#define KSTEP3(D, K)                                                         \
  {                                                                          \
    bf16x8 bf[4];                                                            \
    _Pragma("unroll") for (int ni = 0; ni < 4; ni++) bf[ni] = BR3(D, ni, K); \
    {                                                                        \
      bf16x8 af[4];                                                          \
      _Pragma("unroll") for (int mi = 0; mi < 4; mi++) af[mi] = AR3(D, mi, K);\
      __builtin_amdgcn_s_setprio(1);                                         \
      _Pragma("unroll") for (int ni = 0; ni < 4; ni++)                       \
        _Pragma("unroll") for (int mi = 0; mi < 4; mi++)                     \
          acc[mi][ni] = MFMA16(af[mi], bf[ni], acc[mi][ni]);                 \
      __builtin_amdgcn_s_setprio(0);                                         \
    }                                                                        \
    {                                                                        \
      bf16x8 af[4];                                                          \
      _Pragma("unroll") for (int mi = 0; mi < 4; mi++)                       \
        af[mi] = AR3(D, 4 + mi, K);                                          \
      __builtin_amdgcn_s_setprio(1);                                         \
      _Pragma("unroll") for (int ni = 0; ni < 4; ni++)                       \
        _Pragma("unroll") for (int mi = 0; mi < 4; mi++)                     \
          acc[4 + mi][ni] = MFMA16(af[mi], bf[ni], acc[4 + mi][ni]);         \
      __builtin_amdgcn_s_setprio(0);                                         \
    }                                                                        \
  }

#define KT3(D, T)                                                            \
  {                                                                          \
    stg(0, (D) ^ 1, (T) + 1); stg(1, (D) ^ 1, (T) + 1);                      \
    stg(2, (D) ^ 1, (T) + 1); stg(3, (D) ^ 1, (T) + 1);                      \
    __builtin_amdgcn_sched_barrier(0);                                       \
    KSTEP3(D, 0)                                                             \
    KSTEP3(D, 1)                                                             \
    VM0;                                                                     \
    __builtin_amdgcn_s_barrier();                                            \
    __builtin_amdgcn_sched_barrier(0);                                       \
  }

  // prologue: stage tile0 -> buf0
  stg(0, 0, 0); stg(1, 0, 0); stg(2, 0, 0); stg(3, 0, 0);
  VM0;
  __builtin_amdgcn_s_barrier();
  __builtin_amdgcn_sched_barrier(0);

#pragma unroll 1
  for (int I = 0; I < 8; ++I) {
    KT3(0, 2 * I)
    KT3(1, 2 * I + 1)
  }
#undef KT3
#undef KSTEP3
#undef AR3
#undef BR3

  // ---- fused epilogue (per-wave 128x64 at bm+wr*128, bn+wc*64) ----
  const int rb = bm + wr * 128 + quad * 4;
  const int cb = bn + wc * 64 + lcol;
  if (bn >= 2048) {
#pragma unroll
    for (int ai = 0; ai < 8; ai++) {
#pragma unroll
      for (int bj = 0; bj < 4; bj++) {
        int row0 = rb + ai * 16;
        int s = row0 & (Sn - 1);
        int bb = row0 >> 11;
        int vcol = cb + bj * 16 - 2048;
        int bh = (bb << 4) + (vcol >> 6);
        int hd = vcol & 63;
        unsigned d0 = (unsigned)f2bf(acc[ai][bj][0]) |
                      ((unsigned)f2bf(acc[ai][bj][1]) << 16);
        unsigned d1 = (unsigned)f2bf(acc[ai][bj][2]) |
                      ((unsigned)f2bf(acc[ai][bj][3]) << 16);
        *(uint2*)(vt + ((size_t)bh * HDn + hd) * Sn + s) = (uint2){d0, d1};
      }
    }
  } else {
    const float scale = (bn < 1024) ? qscale : 1.0f;
#pragma unroll
    for (int ai = 0; ai < 8; ai++) {
#pragma unroll
      for (int bj = 0; bj < 4; bj++) {
        int row0 = rb + ai * 16;
        int col = cb + bj * 16;
#pragma unroll
        for (int r = 0; r < 4; r++)
          qkb[(size_t)(row0 + r) * 2048 + col] = f2bf(acc[ai][bj][r] * scale);
      }
    }
  }
}

// ==== output gemm (frozen): 128x256 / BK=64 / triple-buffer ====
#define SRCP_INIT(APTR, BPTR)                                                \
  const u16* srcp[3][2];                                                     \
  _Pragma("unroll") for (int rg = 0; rg < 3; rg++) {                         \
    _Pragma("unroll") for (int j = 0; j < 2; j++) {                          \
      int o = j * 8192 + tid * 16;                                           \
      int l = o ^ (((o >> 8) & 7) << 4);                                     \
      int rho = l >> 7;                                                      \
      int c2 = (l >> 1) & 63;                                                \
      int gr;                                                                \
      if (rg == 0)      gr = bm + rho;                                       \
      else if (rg == 1) gr = bn + ((rho >> 5) << 6) + (rho & 31);            \
      else              gr = bn + ((rho >> 5) << 6) + 32 + (rho & 31);       \
      const u16* base = (rg == 0) ? (APTR) : (BPTR);                         \
      srcp[rg][j] = base + (size_t)gr * Dn + c2;                             \
    }                                                                        \
  }

#define ARD(D, Q, F, K)                                                      \
  (*(const bf16x8*)((const char*)&S[D][0][0] +                               \
      ((wr * 64 + (Q) * 32 + (F) * 16 + lcol) * 128 + ((K) ? cs1 : cs0))))
#define BRD(D, NI, K)                                                        \
  (*(const bf16x8*)((const char*)&S[D][1 + ((NI) >> 1)][0] +                 \
      ((wc * 32 + ((NI) & 1) * 16 + lcol) * 128 + ((K) ? cs1 : cs0))))

#define KTILE(D, DN, T, WAIT)                                                \
  {                                                                          \
    stg(0, DN, (T) + 2); stg(1, DN, (T) + 2); stg(2, DN, (T) + 2);           \
    __builtin_amdgcn_sched_barrier(0);                                       \
    bf16x8 a00 = ARD(D, 0, 0, 0), a10 = ARD(D, 0, 1, 0);                     \
    bf16x8 a20 = ARD(D, 1, 0, 0), a30 = ARD(D, 1, 1, 0);                     \
    bf16x8 bk0[4], bk1[4];                                                   \
    _Pragma("unroll") for (int ni = 0; ni < 4; ni++) bk0[ni] = BRD(D, ni, 0);\
    bf16x8 a01 = ARD(D, 0, 0, 1), a11 = ARD(D, 0, 1, 1);                     \
    bf16x8 a21 = ARD(D, 1, 0, 1), a31 = ARD(D, 1, 1, 1);                     \
    _Pragma("unroll") for (int ni = 0; ni < 4; ni++) bk1[ni] = BRD(D, ni, 1);\
    __builtin_amdgcn_s_setprio(1);                                           \
    _Pragma("unroll") for (int ni = 0; ni < 4; ni++) {                       \
      acc[0][ni] = MFMA16(a00, bk0[ni], acc[0][ni]);                         \
      acc[1][ni] = MFMA16(a10, bk0[ni], acc[1][ni]);                         \
      acc[2][ni] = MFMA16(a20, bk0[ni], acc[2][ni]);                         \
      acc[3][ni] = MFMA16(a30, bk0[ni], acc[3][ni]);                         \
    }                                                                        \
    _Pragma("unroll") for (int ni = 0; ni < 4; ni++) {                       \
      acc[0][ni] = MFMA16(a01, bk1[ni], acc[0][ni]);                         \
      acc[1][ni] = MFMA16(a11, bk1[ni], acc[1][ni]);                         \
      acc[2][ni] = MFMA16(a21, bk1[ni], acc[2][ni]);                         \
      acc[3][ni] = MFMA16(a31, bk1[ni], acc[3][ni]);                         \
    }                                                                        \
    __builtin_amdgcn_s_setprio(0);                                           \
    WAIT;                                                                    \
    __builtin_amdgcn_s_barrier();                                            \
    __builtin_amdgcn_sched_barrier(0);                                       \
  }

#define KLOOP                                                                \
  stg(0, 0, 0); stg(1, 0, 0); stg(2, 0, 0);                                  \
  stg(0, 1, 1); stg(1, 1, 1); stg(2, 1, 1);                                  \
  VM6;                                                                       \
  __builtin_amdgcn_s_barrier();                                              \
  __builtin_amdgcn_sched_barrier(0);                                         \
  _Pragma("unroll 1") for (int I = 0; I < 5; ++I) {                          \
    const int T0 = 3 * I;                                                    \
    KTILE(0, 2, T0, VM6)                                                     \
    KTILE(1, 0, T0 + 1, VM6)                                                 \
    KTILE(2, 1, T0 + 2, if (I == 4) { VM0; } else { VM6; })                  \
  }                                                                          \
  KTILE(0, 2, 15, )

__global__ __launch_bounds__(512, 2) void gemm_out(const u16* __restrict__ A,
                                                   const u16* __restrict__ Bt,
                                                   float* __restrict__ Cout,
                                                   const float* __restrict__ bias) {
  __shared__ __attribute__((aligned(16))) u16 S[3][3][8192];  // 144 KB

  const int tid = threadIdx.x;
  const int lane = tid & 63;
  const int lcol = lane & 15;
  const int quad = lane >> 4;
  const int wave = tid >> 6;
  const int wr = wave >> 2;  // 0..1 (M)
  const int wc = wave & 3;   // 0..3 (N)

  const int bid = blockIdx.x;
  const int idx = bid >> 3;                             // 0..31
  const int bm = (((bid & 7) << 3) + (idx & 7)) * 128;  // M tile 0..63
  const int bn = (idx >> 3) * 256;                      // N tile 0..3

  SRCP_INIT(A, Bt)

  auto stg = [&](int rg, int buf, int tile) {
    if (tile >= 16) return;
    const int k0 = tile << 6;
    u16* d = &S[buf][rg][tid * 8];
    gl2lds16(srcp[rg][0] + k0, d);
    gl2lds16(srcp[rg][1] + k0, d + 4096);
  };

  f32x4 acc[4][4];
#pragma unroll
  for (int i = 0; i < 4; i++)
#pragma unroll
    for (int j = 0; j < 4; j++) acc[i][j] = (f32x4){0.f, 0.f, 0.f, 0.f};

  const int SW = (lcol & 14) << 3;
  const int cs0 = (quad * 16) ^ SW;
  const int cs1 = (64 + quad * 16) ^ SW;

  KLOOP

  // ---- epilogue: fp32 + bias ----
  const int rb = bm + wr * 64 + quad * 4;
  const int cb = bn + wc * 64 + lcol;
  float bv[4];
#pragma unroll
  for (int ni = 0; ni < 4; ni++) bv[ni] = bias[cb + ni * 16];
#pragma unroll
  for (int mi = 0; mi < 4; mi++) {
#pragma unroll
    for (int ni = 0; ni < 4; ni++) {
      int row0 = rb + mi * 16;
      int col = cb + ni * 16;
#pragma unroll
      for (int r = 0; r < 4; r++)
        Cout[(size_t)(row0 + r) * Dn + col] = acc[mi][ni][r] + bv[ni];
    }
  }
}

// ---- causal flash attention v8 (frozen from R8) ----
__global__ __launch_bounds__(256, 2) void attn5(const u16* __restrict__ QK,
                                                const u16* __restrict__ Vt,
                                                u16* __restrict__ ctx) {
  __shared__ __attribute__((aligned(16))) u16 Ks2[2][2][64][32];   // 16 KB
  __shared__ __attribute__((aligned(16))) u16 Vts2[2][2][64][32];  // 16 KB
  __shared__ __attribute__((aligned(16))) u16 Pt[2][4][32][72];    // 36 KB

  const int bh = blockIdx.x;
  const int b = bh >> 4, h = bh & 15;
  const int pair = blockIdx.y;           // 0..7
  const int t = threadIdx.x;
  const int w = t >> 6;
  const int lane = t & 63;
  const int lcol = lane & 15;
  const int quad = lane >> 4;
  const int qw0 = pair * 128 + w * 32;          // short strip wave base
  const int qw1 = (15 - pair) * 128 + w * 32;   // long strip wave base

  const size_t qkbase = ((size_t)b * Sn) * 2048 + h * HDn;
  const size_t obase = ((size_t)b * Sn) * Dn + h * HDn;
  const size_t vbase = ((size_t)bh * HDn) * Sn;

  bf16x8 qf[2][2][2];  // [strip][qb][kc]
#pragma unroll
  for (int si = 0; si < 2; si++) {
    const int qws = si ? qw1 : qw0;
#pragma unroll
    for (int qb = 0; qb < 2; qb++) {
      const u16* qp = QK + qkbase + (size_t)(qws + qb * 16 + lcol) * 2048 + quad * 8;
      qf[si][qb][0] = *(const bf16x8*)qp;
      qf[si][qb][1] = *(const bf16x8*)(qp + 32);
    }
  }

  bf16x8 onesf;
#pragma unroll
  for (int i = 0; i < 8; i++) onesf[i] = (__bf16)1.0f;

  f32x4 o[2][2][4];   // [strip][qb][nb]
  f32x4 ls[2][2];     // [strip][qb] MFMA row-sum accumulators
#pragma unroll
  for (int si = 0; si < 2; si++) {
#pragma unroll
    for (int qb = 0; qb < 2; qb++) {
      ls[si][qb] = (f32x4){0.f, 0.f, 0.f, 0.f};
#pragma unroll
      for (int nb = 0; nb < 4; nb++) o[si][qb][nb] = (f32x4){0.f, 0.f, 0.f, 0.f};
    }
  }

  const int srow = lane >> 2;
  const int sseg = ((lane & 3) ^ ((lane >> 3) & 3)) * 8;
  const u16* kp0 = QK + qkbase + 1024 + (size_t)(w * 16 + srow) * 2048 + sseg;
  const u16* vp0 = Vt + vbase + (size_t)(w * 16 + srow) * Sn + sseg;
  u16* ksl = &Ks2[0][0][0][0] + w * 512 + lane * 8;
  u16* vsl = &Vts2[0][0][0][0] + w * 512 + lane * 8;

  const int rsw = (quad ^ ((lcol >> 1) & 3)) * 8;

  auto stg_kv = [&](int bs, int j0) {
    const u16* kp = kp0 + (size_t)j0 * 2048;
    const u16* vp = vp0 + j0;
    u16* kd = ksl + bs * 4096;
    u16* vd = vsl + bs * 4096;
    gl2lds16(kp, kd);
    gl2lds16(kp + 32, kd + 2048);
    gl2lds16(vp, vd);
    gl2lds16(vp + 32, vd + 2048);
  };

  auto qk_strip = [&](int si, f32x4 (*s)[2], int bs) {
    __builtin_amdgcn_s_setprio(1);
#pragma unroll
    for (int mb = 0; mb < 4; mb++) {
      bf16x8 kf0 = *(const bf16x8*)(&Ks2[bs][0][mb * 16 + lcol][rsw]);
      bf16x8 kf1 = *(const bf16x8*)(&Ks2[bs][1][mb * 16 + lcol][rsw]);
#pragma unroll
      for (int qb = 0; qb < 2; qb++) {
        f32x4 a = (f32x4){0.f, 0.f, 0.f, 0.f};
        a = MFMA16(kf0, qf[si][qb][0], a);
        a = MFMA16(kf1, qf[si][qb][1], a);
        s[mb][qb] = a;
      }
    }
    __builtin_amdgcn_s_setprio(0);
  };

  auto sm_strip = [&](int si, int qw, int j0, f32x4 (*s)[2]) {
    const bool needmask = (j0 + 63 > qw);
#pragma unroll
    for (int qb = 0; qb < 2; qb++) {
      const int qrow = qw + qb * 16 + lcol;
#pragma unroll
      for (int mb = 0; mb < 4; mb++) {
        float p[4];
#pragma unroll
        for (int r = 0; r < 4; r++) p[r] = fexp2(s[mb][qb][r]);
        if (needmask) {
          const int kvb = j0 + mb * 16 + quad * 4;
#pragma unroll
          for (int r = 0; r < 4; r++)
            if (kvb + r > qrow) p[r] = 0.f;
        }
        unsigned d0 = pk_bf_trunc(p[0], p[1]);
        unsigned d1 = pk_bf_trunc(p[2], p[3]);
        *(uint2*)(&Pt[si][w][qb * 16 + lcol][mb * 16 + quad * 4]) = (uint2){d0, d1};
      }
    }
  };

  auto pv_strip = [&](int si, int bs) {
    __builtin_amdgcn_s_setprio(1);
#pragma unroll
    for (int c = 0; c < 2; c++) {
      bf16x8 pf0 = *(const bf16x8*)(&Pt[si][w][lcol][c * 32 + quad * 8]);
      bf16x8 pf1 = *(const bf16x8*)(&Pt[si][w][16 + lcol][c * 32 + quad * 8]);
      ls[si][0] = MFMA16(onesf, pf0, ls[si][0]);
      ls[si][1] = MFMA16(onesf, pf1, ls[si][1]);
#pragma unroll
      for (int nb = 0; nb < 4; nb++) {
        bf16x8 vf = *(const bf16x8*)(&Vts2[bs][c][nb * 16 + lcol][rsw]);
        o[si][0][nb] = MFMA16(vf, pf0, o[si][0][nb]);
        o[si][1][nb] = MFMA16(vf, pf1, o[si][1][nb]);
      }
    }
    __builtin_amdgcn_s_setprio(0);
  };

  const int n_kv = (15 - pair) * 128 + 128;  // long strip upper bound
  const int nit = n_kv >> 6;

  stg_kv(0, 0);
#pragma unroll 1
  for (int it = 0; it < nit; ++it) {
    const int j0 = it << 6;
    const int bs = it & 1;
    if (it + 1 < nit) {
      stg_kv(bs ^ 1, j0 + 64);
      asm volatile("s_waitcnt vmcnt(4)" ::: "memory");
    } else {
      asm volatile("s_waitcnt vmcnt(0)" ::: "memory");
    }
    __builtin_amdgcn_s_barrier();
    __builtin_amdgcn_sched_barrier(0);

    const bool a0 = (j0 <= qw0 + 31);
    f32x4 s1[4][2], s0[4][2];
    qk_strip(1, s1, bs);
    if (a0) qk_strip(0, s0, bs);
    sm_strip(1, qw1, j0, s1);
    if (a0) sm_strip(0, qw0, j0, s0);
    pv_strip(1, bs);
    if (a0) pv_strip(0, bs);

    __builtin_amdgcn_s_barrier();
    __builtin_amdgcn_sched_barrier(0);
  }

#pragma unroll
  for (int si = 0; si < 2; si++) {
    const int qws = si ? qw1 : qw0;
#pragma unroll
    for (int qb = 0; qb < 2; qb++) {
      float inv = 1.0f / ls[si][qb][0];
#pragma unroll
      for (int nb = 0; nb < 4; nb++) {
        unsigned d0 = (unsigned)f2bf(o[si][qb][nb][0] * inv) |
                      ((unsigned)f2bf(o[si][qb][nb][1] * inv) << 16);
        unsigned d1 = (unsigned)f2bf(o[si][qb][nb][2] * inv) |
                      ((unsigned)f2bf(o[si][qb][nb][3] * inv) << 16);
        u16* p = ctx + obase + (size_t)(qws + qb * 16 + lcol) * Dn + nb * 16 + quad * 4;
        *(uint2*)p = (uint2){d0, d1};
      }
    }
  }
}

extern "C" void kernel_launch(void* const* d_in, const int* in_sizes, int n_in,
                              void* d_out, int out_size, void* d_ws, size_t ws_size,
                              hipStream_t stream) {
  const float* x  = (const float*)d_in[0];
  const float* Wq = (const float*)d_in[1];
  const float* Wk = (const float*)d_in[2];
  const float* Wv = (const float*)d_in[3];
  const float* Wo = (const float*)d_in[4];
  const float* bo = (const float*)d_in[5];
  float* out = (float*)d_out;

  const size_t BSD = (size_t)Bn * Sn * Dn;
  const size_t DD = (size_t)Dn * Dn;

  u16* xb    = (u16*)d_ws;           // BSD
  u16* wall  = xb + BSD;             // 4*DD  (Wq^T, Wk^T, Wv^T, Wo^T)
  u16* qkb   = wall + 4 * DD;        // 2*BSD
  u16* vt    = qkb + 2 * BSD;        // BSD
  u16* cb    = vt + BSD;             // BSD

  cvt4<<<(int)(BSD / 4 / 256), 256, 0, stream>>>(x, xb, (int)(BSD / 4));
  tcvt4<<<dim3(Dn / 32, Dn / 32, 4), 256, 0, stream>>>(Wq, Wk, Wv, Wo, wall);

  // fused QKV projection: 256x256 tiles, 384 blocks, double-buffer (v3)
  gemm_qkv<<<dim3(384), 512, 0, stream>>>(xb, wall, qkb, vt,
                                          0.125f * 1.44269504f);

  attn5<<<dim3(Bn * Hn, 8), 256, 0, stream>>>(qkb, vt, cb);

  // output projection: 128x256 tiles, 256 blocks (1 perfect round)
  gemm_out<<<dim3(256), 512, 0, stream>>>(cb, wall + 3 * DD, out, bo);
}

// Round 11
// 226.683 us; speedup vs baseline: 1.2890x; 1.0582x over previous
//
#include <hip/hip_runtime.h>

typedef unsigned short u16;
typedef __bf16 bf16x8 __attribute__((ext_vector_type(8)));
typedef float f32x4 __attribute__((ext_vector_type(4)));

#define Bn 4
#define Sn 2048
#define Dn 1024
#define Hn 16
#define HDn 64

__device__ inline u16 f2bf(float f) {
  unsigned u = __builtin_bit_cast(unsigned, f);
  u += 0x7fffu + ((u >> 16) & 1u);
  return (u16)(u >> 16);
}

// async global->LDS DMA, 16B/lane; LDS dest = wave base + lane*16 [m97]
__device__ __forceinline__ void gl2lds16(const u16* g, u16* l) {
  __builtin_amdgcn_global_load_lds(
      (const __attribute__((address_space(1))) unsigned int*)g,
      (__attribute__((address_space(3))) unsigned int*)l, 16, 0, 0);
}

__device__ __forceinline__ float fexp2(float x) {
  return __builtin_amdgcn_exp2f(x);
}

// pack two f32 -> two bf16 (truncating) in one v_perm
__device__ __forceinline__ unsigned pk_bf_trunc(float lo, float hi) {
  return __builtin_amdgcn_perm(__builtin_bit_cast(unsigned, hi),
                               __builtin_bit_cast(unsigned, lo), 0x07060302u);
}

// ---- merged prep: cvt (blocks 0..8191) + weight transpose (8192..12287) ----
// Saves one kernel launch + its gap vs separate cvt4/tcvt4.
__global__ __launch_bounds__(256) void prep(const float* __restrict__ x,
                                            u16* __restrict__ xb,
                                            const float* __restrict__ w0,
                                            const float* __restrict__ w1,
                                            const float* __restrict__ w2,
                                            const float* __restrict__ w3,
                                            u16* __restrict__ wall) {
  __shared__ u16 tile[32][33];
  const int blk = blockIdx.x;
  if (blk < 8192) {
    int i = blk * 256 + threadIdx.x;  // n4 = 8192*256 exactly
    float4 v = ((const float4*)x)[i];
    ushort4 o;
    o.x = f2bf(v.x); o.y = f2bf(v.y); o.z = f2bf(v.z); o.w = f2bf(v.w);
    ((ushort4*)xb)[i] = o;
  } else {
    const int rem = blk - 8192;            // 0..4095 = 32 x 32 x 4
    const int bx = (rem & 31) * 32;
    const int by = ((rem >> 5) & 31) * 32;
    const int z = rem >> 10;
    const float* in = (z == 0) ? w0 : (z == 1) ? w1 : (z == 2) ? w2 : w3;
    u16* dst = wall + (size_t)z * Dn * Dn;
    int tx = threadIdx.x & 31;
    int ty = threadIdx.x >> 5;
#pragma unroll
    for (int r = 0; r < 32; r += 8)
      tile[ty + r][tx] = f2bf(in[(size_t)(by + ty + r) * Dn + bx + tx]);
    __syncthreads();
#pragma unroll
    for (int r = 0; r < 32; r += 8)
      dst[(size_t)(bx + ty + r) * Dn + by + tx] = tile[tx][ty + r];
  }
}

// ==== shared 128x256 / BK=64 / triple-buffer / 1-barrier-per-tile K-loop ====
// Proven best (R6-R8: gemm_qkv 62.0us, 3 perfect rounds, conflicts 0).
// R9/R10's 256^2 arc abandoned: dbuf forces vmcnt(0)/tile (T4 violation) and
// 1.5-round grid executes as 2 rounds; measured 69us > 62us.
#define MFMA16(a, b, c) __builtin_amdgcn_mfma_f32_16x16x32_bf16(a, b, c, 0, 0, 0)
#define VM6 asm volatile("s_waitcnt vmcnt(6)" ::: "memory")
#define VM0 asm volatile("s_waitcnt vmcnt(0)" ::: "memory")

#define SRCP_INIT(APTR, BPTR)                                                \
  const u16* srcp[3][2];                                                     \
  _Pragma("unroll") for (int rg = 0; rg < 3; rg++) {                         \
    _Pragma("unroll") for (int j = 0; j < 2; j++) {                          \
      int o = j * 8192 + tid * 16;                                           \
      int l = o ^ (((o >> 8) & 7) << 4);                                     \
      int rho = l >> 7;                                                      \
      int c2 = (l >> 1) & 63;                                                \
      int gr;                                                                \
      if (rg == 0)      gr = bm + rho;                                       \
      else if (rg == 1) gr = bn + ((rho >> 5) << 6) + (rho & 31);            \
      else              gr = bn + ((rho >> 5) << 6) + 32 + (rho & 31);       \
      const u16* base = (rg == 0) ? (APTR) : (BPTR);                         \
      srcp[rg][j] = base + (size_t)gr * Dn + c2;                             \
    }                                                                        \
  }

#define ARD(D, Q, F, K)                                                      \
  (*(const bf16x8*)((const char*)&S[D][0][0] +                               \
      ((wr * 64 + (Q) * 32 + (F) * 16 + lcol) * 128 + ((K) ? cs1 : cs0))))
#define BRD(D, NI, K)                                                        \
  (*(const bf16x8*)((const char*)&S[D][1 + ((NI) >> 1)][0] +                 \
      ((wc * 32 + ((NI) & 1) * 16 + lcol) * 128 + ((K) ? cs1 : cs0))))

#define KTILE(D, DN, T, WAIT)                                                \
  {                                                                          \
    stg(0, DN, (T) + 2); stg(1, DN, (T) + 2); stg(2, DN, (T) + 2);           \
    __builtin_amdgcn_sched_barrier(0);                                       \
    bf16x8 a00 = ARD(D, 0, 0, 0), a10 = ARD(D, 0, 1, 0);                     \
    bf16x8 a20 = ARD(D, 1, 0, 0), a30 = ARD(D, 1, 1, 0);                     \
    bf16x8 bk0[4], bk1[4];                                                   \
    _Pragma("unroll") for (int ni = 0; ni < 4; ni++) bk0[ni] = BRD(D, ni, 0);\
    bf16x8 a01 = ARD(D, 0, 0, 1), a11 = ARD(D, 0, 1, 1);                     \
    bf16x8 a21 = ARD(D, 1, 0, 1), a31 = ARD(D, 1, 1, 1);                     \
    _Pragma("unroll") for (int ni = 0; ni < 4; ni++) bk1[ni] = BRD(D, ni, 1);\
    __builtin_amdgcn_s_setprio(1);                                           \
    _Pragma("unroll") for (int ni = 0; ni < 4; ni++) {                       \
      acc[0][ni] = MFMA16(a00, bk0[ni], acc[0][ni]);                         \
      acc[1][ni] = MFMA16(a10, bk0[ni], acc[1][ni]);                         \
      acc[2][ni] = MFMA16(a20, bk0[ni], acc[2][ni]);                         \
      acc[3][ni] = MFMA16(a30, bk0[ni], acc[3][ni]);                         \
    }                                                                        \
    _Pragma("unroll") for (int ni = 0; ni < 4; ni++) {                       \
      acc[0][ni] = MFMA16(a01, bk1[ni], acc[0][ni]);                         \
      acc[1][ni] = MFMA16(a11, bk1[ni], acc[1][ni]);                         \
      acc[2][ni] = MFMA16(a21, bk1[ni], acc[2][ni]);                         \
      acc[3][ni] = MFMA16(a31, bk1[ni], acc[3][ni]);                         \
    }                                                                        \
    __builtin_amdgcn_s_setprio(0);                                           \
    WAIT;                                                                    \
    __builtin_amdgcn_s_barrier();                                            \
    __builtin_amdgcn_sched_barrier(0);                                       \
  }

#define KLOOP                                                                \
  stg(0, 0, 0); stg(1, 0, 0); stg(2, 0, 0);                                  \
  stg(0, 1, 1); stg(1, 1, 1); stg(2, 1, 1);                                  \
  VM6;                                                                       \
  __builtin_amdgcn_s_barrier();                                              \
  __builtin_amdgcn_sched_barrier(0);                                         \
  _Pragma("unroll 1") for (int I = 0; I < 5; ++I) {                          \
    const int T0 = 3 * I;                                                    \
    KTILE(0, 2, T0, VM6)                                                     \
    KTILE(1, 0, T0 + 1, VM6)                                                 \
    KTILE(2, 1, T0 + 2, if (I == 4) { VM0; } else { VM6; })                  \
  }                                                                          \
  KTILE(0, 2, 15, )

// ==== fused QKV gemm (R8-exact revert): M=8192, N=3072, 768 blocks ====
__global__ __launch_bounds__(512, 2) void gemm_qkv(const u16* __restrict__ A,
                                                   const u16* __restrict__ Bt,
                                                   u16* __restrict__ qkb,
                                                   u16* __restrict__ vt,
                                                   float qscale) {
  __shared__ __attribute__((aligned(16))) u16 S[3][3][8192];  // 144 KB

  const int tid = threadIdx.x;
  const int lane = tid & 63;
  const int lcol = lane & 15;
  const int quad = lane >> 4;
  const int wave = tid >> 6;
  const int wr = wave >> 2;  // 0..1 (M)
  const int wc = wave & 3;   // 0..3 (N)

  // XCD swizzle: xcd = bid&7 owns M-tiles xcd*8..+7 across all 12 N-tiles.
  const int bid = blockIdx.x;
  const int idx = bid >> 3;                             // 0..95
  const int bm = (((bid & 7) << 3) + (idx & 7)) * 128;  // M tile 0..63
  const int bn = (idx >> 3) * 256;                      // N tile 0..11

  SRCP_INIT(A, Bt)

  auto stg = [&](int rg, int buf, int tile) {
    if (tile >= 16) return;  // tail guard (tiles 16,17)
    const int k0 = tile << 6;
    u16* d = &S[buf][rg][tid * 8];
    gl2lds16(srcp[rg][0] + k0, d);
    gl2lds16(srcp[rg][1] + k0, d + 4096);
  };

  f32x4 acc[4][4];
#pragma unroll
  for (int i = 0; i < 4; i++)
#pragma unroll
    for (int j = 0; j < 4; j++) acc[i][j] = (f32x4){0.f, 0.f, 0.f, 0.f};

  const int SW = (lcol & 14) << 3;
  const int cs0 = (quad * 16) ^ SW;
  const int cs1 = (64 + quad * 16) ^ SW;

  KLOOP

  // ---- fused epilogue (per-wave 64x64 at bm+wr*64, bn+wc*64) ----
  const int rb = bm + wr * 64 + quad * 4;
  const int cb = bn + wc * 64 + lcol;
  if (bn >= 2048) {
#pragma unroll
    for (int mi = 0; mi < 4; mi++) {
#pragma unroll
      for (int ni = 0; ni < 4; ni++) {
        int row0 = rb + mi * 16;
        int s = row0 & (Sn - 1);
        int bb = row0 >> 11;
        int vcol = cb + ni * 16 - 2048;
        int bh = (bb << 4) + (vcol >> 6);
        int hd = vcol & 63;
        unsigned d0 = (unsigned)f2bf(acc[mi][ni][0]) |
                      ((unsigned)f2bf(acc[mi][ni][1]) << 16);
        unsigned d1 = (unsigned)f2bf(acc[mi][ni][2]) |
                      ((unsigned)f2bf(acc[mi][ni][3]) << 16);
        *(uint2*)(vt + ((size_t)bh * HDn + hd) * Sn + s) = (uint2){d0, d1};
      }
    }
  } else {
    const float scale = (bn < 1024) ? qscale : 1.0f;
#pragma unroll
    for (int mi = 0; mi < 4; mi++) {
#pragma unroll
      for (int ni = 0; ni < 4; ni++) {
        int row0 = rb + mi * 16;
        int col = cb + ni * 16;
#pragma unroll
        for (int r = 0; r < 4; r++)
          qkb[(size_t)(row0 + r) * 2048 + col] = f2bf(acc[mi][ni][r] * scale);
      }
    }
  }
}

// ==== output gemm (frozen): M=8192, N=1024, 256 blocks = 1 perfect round ====
__global__ __launch_bounds__(512, 2) void gemm_out(const u16* __restrict__ A,
                                                   const u16* __restrict__ Bt,
                                                   float* __restrict__ Cout,
                                                   const float* __restrict__ bias) {
  __shared__ __attribute__((aligned(16))) u16 S[3][3][8192];  // 144 KB

  const int tid = threadIdx.x;
  const int lane = tid & 63;
  const int lcol = lane & 15;
  const int quad = lane >> 4;
  const int wave = tid >> 6;
  const int wr = wave >> 2;  // 0..1 (M)
  const int wc = wave & 3;   // 0..3 (N)

  const int bid = blockIdx.x;
  const int idx = bid >> 3;                             // 0..31
  const int bm = (((bid & 7) << 3) + (idx & 7)) * 128;  // M tile 0..63
  const int bn = (idx >> 3) * 256;                      // N tile 0..3

  SRCP_INIT(A, Bt)

  auto stg = [&](int rg, int buf, int tile) {
    if (tile >= 16) return;
    const int k0 = tile << 6;
    u16* d = &S[buf][rg][tid * 8];
    gl2lds16(srcp[rg][0] + k0, d);
    gl2lds16(srcp[rg][1] + k0, d + 4096);
  };

  f32x4 acc[4][4];
#pragma unroll
  for (int i = 0; i < 4; i++)
#pragma unroll
    for (int j = 0; j < 4; j++) acc[i][j] = (f32x4){0.f, 0.f, 0.f, 0.f};

  const int SW = (lcol & 14) << 3;
  const int cs0 = (quad * 16) ^ SW;
  const int cs1 = (64 + quad * 16) ^ SW;

  KLOOP

  // ---- epilogue: fp32 + bias ----
  const int rb = bm + wr * 64 + quad * 4;
  const int cb = bn + wc * 64 + lcol;
  float bv[4];
#pragma unroll
  for (int ni = 0; ni < 4; ni++) bv[ni] = bias[cb + ni * 16];
#pragma unroll
  for (int mi = 0; mi < 4; mi++) {
#pragma unroll
    for (int ni = 0; ni < 4; ni++) {
      int row0 = rb + mi * 16;
      int col = cb + ni * 16;
#pragma unroll
      for (int r = 0; r < 4; r++)
        Cout[(size_t)(row0 + r) * Dn + col] = acc[mi][ni][r] + bv[ni];
    }
  }
}

// ---- causal flash attention v9: full bank-spread K/V swizzle ----
// R7's swizzle (row bits 1-2 -> slot) halved conflicts 7.57M->3.24M; the
// residual is 4-way aliasing across the 32-lane half: lanes 8 apart (row
// bit 3 differs) map to the same bank-quad. v9 adds row bit 3 into slot
// bit 1 of the involution on BOTH sides (rule #21): bank algebra gives
// exactly 2 lanes per bank-quad per 32-lane cycle = free [m136].
//   stage source slot: (lane&3) ^ ((lane>>3)&3) ^ ((lane>>4)&2)
//   read slot:         quad ^ ((lcol>>1)&3) ^ ((lcol>>2)&2)
// Everything else frozen from R8 (strip interleave, MFMA-lsum, setprio).
__global__ __launch_bounds__(256, 2) void attn5(const u16* __restrict__ QK,
                                                const u16* __restrict__ Vt,
                                                u16* __restrict__ ctx) {
  __shared__ __attribute__((aligned(16))) u16 Ks2[2][2][64][32];   // 16 KB
  __shared__ __attribute__((aligned(16))) u16 Vts2[2][2][64][32];  // 16 KB
  __shared__ __attribute__((aligned(16))) u16 Pt[2][4][32][72];    // 36 KB

  const int bh = blockIdx.x;
  const int b = bh >> 4, h = bh & 15;
  const int pair = blockIdx.y;           // 0..7
  const int t = threadIdx.x;
  const int w = t >> 6;
  const int lane = t & 63;
  const int lcol = lane & 15;
  const int quad = lane >> 4;
  const int qw0 = pair * 128 + w * 32;          // short strip wave base
  const int qw1 = (15 - pair) * 128 + w * 32;   // long strip wave base

  const size_t qkbase = ((size_t)b * Sn) * 2048 + h * HDn;
  const size_t obase = ((size_t)b * Sn) * Dn + h * HDn;
  const size_t vbase = ((size_t)bh * HDn) * Sn;

  bf16x8 qf[2][2][2];  // [strip][qb][kc]
#pragma unroll
  for (int si = 0; si < 2; si++) {
    const int qws = si ? qw1 : qw0;
#pragma unroll
    for (int qb = 0; qb < 2; qb++) {
      const u16* qp = QK + qkbase + (size_t)(qws + qb * 16 + lcol) * 2048 + quad * 8;
      qf[si][qb][0] = *(const bf16x8*)qp;
      qf[si][qb][1] = *(const bf16x8*)(qp + 32);
    }
  }

  bf16x8 onesf;
#pragma unroll
  for (int i = 0; i < 8; i++) onesf[i] = (__bf16)1.0f;

  f32x4 o[2][2][4];   // [strip][qb][nb]
  f32x4 ls[2][2];     // [strip][qb] MFMA row-sum accumulators
#pragma unroll
  for (int si = 0; si < 2; si++) {
#pragma unroll
    for (int qb = 0; qb < 2; qb++) {
      ls[si][qb] = (f32x4){0.f, 0.f, 0.f, 0.f};
#pragma unroll
      for (int nb = 0; nb < 4; nb++) o[si][qb][nb] = (f32x4){0.f, 0.f, 0.f, 0.f};
    }
  }

  const int srow = lane >> 2;
  // inverse-swizzled source 16B-slot (adds row bit 3 = lane bit 5)
  const int sseg = ((lane & 3) ^ ((lane >> 3) & 3) ^ ((lane >> 4) & 2)) * 8;
  const u16* kp0 = QK + qkbase + 1024 + (size_t)(w * 16 + srow) * 2048 + sseg;
  const u16* vp0 = Vt + vbase + (size_t)(w * 16 + srow) * Sn + sseg;
  u16* ksl = &Ks2[0][0][0][0] + w * 512 + lane * 8;   // linear dest
  u16* vsl = &Vts2[0][0][0][0] + w * 512 + lane * 8;

  // read-side swizzle (adds row bit 3 = lcol bit 3)
  const int rsw = (quad ^ ((lcol >> 1) & 3) ^ ((lcol >> 2) & 2)) * 8;

  auto stg_kv = [&](int bs, int j0) {
    const u16* kp = kp0 + (size_t)j0 * 2048;
    const u16* vp = vp0 + j0;
    u16* kd = ksl + bs * 4096;
    u16* vd = vsl + bs * 4096;
    gl2lds16(kp, kd);
    gl2lds16(kp + 32, kd + 2048);
    gl2lds16(vp, vd);
    gl2lds16(vp + 32, vd + 2048);
  };

  auto qk_strip = [&](int si, f32x4 (*s)[2], int bs) {
    __builtin_amdgcn_s_setprio(1);
#pragma unroll
    for (int mb = 0; mb < 4; mb++) {
      bf16x8 kf0 = *(const bf16x8*)(&Ks2[bs][0][mb * 16 + lcol][rsw]);
      bf16x8 kf1 = *(const bf16x8*)(&Ks2[bs][1][mb * 16 + lcol][rsw]);
#pragma unroll
      for (int qb = 0; qb < 2; qb++) {
        f32x4 a = (f32x4){0.f, 0.f, 0.f, 0.f};
        a = MFMA16(kf0, qf[si][qb][0], a);
        a = MFMA16(kf1, qf[si][qb][1], a);
        s[mb][qb] = a;
      }
    }
    __builtin_amdgcn_s_setprio(0);
  };

  auto sm_strip = [&](int si, int qw, int j0, f32x4 (*s)[2]) {
    const bool needmask = (j0 + 63 > qw);
#pragma unroll
    for (int qb = 0; qb < 2; qb++) {
      const int qrow = qw + qb * 16 + lcol;
#pragma unroll
      for (int mb = 0; mb < 4; mb++) {
        float p[4];
#pragma unroll
        for (int r = 0; r < 4; r++) p[r] = fexp2(s[mb][qb][r]);
        if (needmask) {
          const int kvb = j0 + mb * 16 + quad * 4;
#pragma unroll
          for (int r = 0; r < 4; r++)
            if (kvb + r > qrow) p[r] = 0.f;
        }
        unsigned d0 = pk_bf_trunc(p[0], p[1]);
        unsigned d1 = pk_bf_trunc(p[2], p[3]);
        *(uint2*)(&Pt[si][w][qb * 16 + lcol][mb * 16 + quad * 4]) = (uint2){d0, d1};
      }
    }
  };

  auto pv_strip = [&](int si, int bs) {
    __builtin_amdgcn_s_setprio(1);
#pragma unroll
    for (int c = 0; c < 2; c++) {
      bf16x8 pf0 = *(const bf16x8*)(&Pt[si][w][lcol][c * 32 + quad * 8]);
      bf16x8 pf1 = *(const bf16x8*)(&Pt[si][w][16 + lcol][c * 32 + quad * 8]);
      ls[si][0] = MFMA16(onesf, pf0, ls[si][0]);
      ls[si][1] = MFMA16(onesf, pf1, ls[si][1]);
#pragma unroll
      for (int nb = 0; nb < 4; nb++) {
        bf16x8 vf = *(const bf16x8*)(&Vts2[bs][c][nb * 16 + lcol][rsw]);
        o[si][0][nb] = MFMA16(vf, pf0, o[si][0][nb]);
        o[si][1][nb] = MFMA16(vf, pf1, o[si][1][nb]);
      }
    }
    __builtin_amdgcn_s_setprio(0);
  };

  const int n_kv = (15 - pair) * 128 + 128;  // long strip upper bound
  const int nit = n_kv >> 6;

  stg_kv(0, 0);
#pragma unroll 1
  for (int it = 0; it < nit; ++it) {
    const int j0 = it << 6;
    const int bs = it & 1;
    if (it + 1 < nit) {
      stg_kv(bs ^ 1, j0 + 64);
      asm volatile("s_waitcnt vmcnt(4)" ::: "memory");
    } else {
      asm volatile("s_waitcnt vmcnt(0)" ::: "memory");
    }
    __builtin_amdgcn_s_barrier();
    __builtin_amdgcn_sched_barrier(0);

    const bool a0 = (j0 <= qw0 + 31);
    f32x4 s1[4][2], s0[4][2];
    qk_strip(1, s1, bs);
    if (a0) qk_strip(0, s0, bs);
    sm_strip(1, qw1, j0, s1);
    if (a0) sm_strip(0, qw0, j0, s0);
    pv_strip(1, bs);
    if (a0) pv_strip(0, bs);

    __builtin_amdgcn_s_barrier();
    __builtin_amdgcn_sched_barrier(0);
  }

#pragma unroll
  for (int si = 0; si < 2; si++) {
    const int qws = si ? qw1 : qw0;
#pragma unroll
    for (int qb = 0; qb < 2; qb++) {
      float inv = 1.0f / ls[si][qb][0];
#pragma unroll
      for (int nb = 0; nb < 4; nb++) {
        unsigned d0 = (unsigned)f2bf(o[si][qb][nb][0] * inv) |
                      ((unsigned)f2bf(o[si][qb][nb][1] * inv) << 16);
        unsigned d1 = (unsigned)f2bf(o[si][qb][nb][2] * inv) |
                      ((unsigned)f2bf(o[si][qb][nb][3] * inv) << 16);
        u16* p = ctx + obase + (size_t)(qws + qb * 16 + lcol) * Dn + nb * 16 + quad * 4;
        *(uint2*)p = (uint2){d0, d1};
      }
    }
  }
}

extern "C" void kernel_launch(void* const* d_in, const int* in_sizes, int n_in,
                              void* d_out, int out_size, void* d_ws, size_t ws_size,
                              hipStream_t stream) {
  const float* x  = (const float*)d_in[0];
  const float* Wq = (const float*)d_in[1];
  const float* Wk = (const float*)d_in[2];
  const float* Wv = (const float*)d_in[3];
  const float* Wo = (const float*)d_in[4];
  const float* bo = (const float*)d_in[5];
  float* out = (float*)d_out;

  const size_t BSD = (size_t)Bn * Sn * Dn;
  const size_t DD = (size_t)Dn * Dn;

  u16* xb    = (u16*)d_ws;           // BSD
  u16* wall  = xb + BSD;             // 4*DD  (Wq^T, Wk^T, Wv^T, Wo^T)
  u16* qkb   = wall + 4 * DD;        // 2*BSD
  u16* vt    = qkb + 2 * BSD;        // BSD
  u16* cb    = vt + BSD;             // BSD

  // merged convert + transpose: 8192 cvt blocks + 4096 transpose blocks
  prep<<<dim3(12288), 256, 0, stream>>>(x, xb, Wq, Wk, Wv, Wo, wall);

  // fused QKV projection: 128x256 tiles, 768 blocks (3 perfect rounds)
  gemm_qkv<<<dim3(768), 512, 0, stream>>>(xb, wall, qkb, vt,
                                          0.125f * 1.44269504f);

  attn5<<<dim3(Bn * Hn, 8), 256, 0, stream>>>(qkb, vt, cb);

  // output projection: 128x256 tiles, 256 blocks (1 perfect round)
  gemm_out<<<dim3(256), 512, 0, stream>>>(cb, wall + 3 * DD, out, bo);
}